// Round 12
// baseline (6311.379 us; speedup 1.0000x reference)
//
#include <hip/hip_runtime.h>

#define B_ 256
#define T_ 512
#define V_ 128
#define E_ 128
#define H_ 256
#define FH 1024

#define GROUPS 32
#define RPG 8      // batch rows per group
#define CWG 16     // packed column-slices per group (layout unchanged)
#define WGPG 8     // column-WGs per group (each covers 2 slices, 512 thr)
#define NWG (GROUPS*WGPG)   // 256 = 1 block/CU

#define HTG 2048   // floats: one group's h, one layer, one buffer ([16c][16gu][8 r'])
#define GST (GROUPS*HTG)   // 65536

typedef float f4 __attribute__((ext_vector_type(4)));
typedef unsigned long long ull;

// ---- workspace layout (float offsets) ----
#define OFF_HT0  0                              // h0 [2buf][grp][c][gu][r']
#define OFF_HT1  (OFF_HT0 + 2*GST)
#define OFF_BAR  (OFF_HT1 + 2*GST)              // 32 groups * 1024 uints (4KB/grp)
#define BARSZ    (GROUPS*1024)                  // fA_c at [c*32], fB_c at [c*32+16]; xcc at [512+cc]
#define OFF_TP   (OFF_BAR + BARSZ)              // TokProj [V][1024] packed
#define OFF_CP   (OFF_TP + V_*FH)               // ClusProj [B][1024] packed (+b0)
#define OFF_WP0  (OFF_CP + B_*FH)               // W0h x4-packed [16c][64kb][64lane][4j]
#define OFF_WP1  (OFF_WP0 + CWG*64*64*4)        // W1  x4-packed [16c][128kb][64lane][4j]
#define OFF_DWT  (OFF_WP1 + CWG*128*64*4)       // decoderW^T [128v][256k]
#define OFF_B1   (OFF_DWT + V_*H_)              // b1 packed [1024]
#define OFF_PERM (OFF_B1 + FH)                  // row permutation [256] (ints)

// packed column order: local col = u*4+g  ->  global z-col G = g*256 + c*16 + u
__device__ __forceinline__ int gcol(int c, int col) {
  int u = col >> 2, g = col & 3;
  return g*256 + c*16 + u;
}

__device__ __forceinline__ float sigm(float x){ return 1.f/(1.f+__expf(-x)); }
__device__ __forceinline__ float tanh_(float x){ return 1.f - 2.f/(1.f+__expf(2.f*x)); }

// ============ prep kernels ============

__global__ void prep_pack(const float* __restrict__ W0, const float* __restrict__ W1,
                          const float* __restrict__ dW, const float* __restrict__ b1,
                          float* __restrict__ ws) {
  float* wp0 = ws + OFF_WP0; float* wp1 = ws + OFF_WP1;
  float* dwT = ws + OFF_DWT; float* b1p = ws + OFF_B1;
  const int N0 = CWG*64*64*4;     // 262144
  const int N1 = CWG*128*64*4;    // 524288
  const int N2 = V_*H_;           // 32768
  const int N3 = FH;              // 1024
  const int total = N0+N1+N2+N3;
  for (int i = blockIdx.x*blockDim.x + threadIdx.x; i < total; i += gridDim.x*blockDim.x) {
    if (i < N0) {
      int cc = i >> 14; int rem = i & 16383;
      int kb = rem >> 8; int ln = (rem >> 2) & 63; int j = i & 3;
      int k = kb*4 + j;
      wp0[i] = W0[(E_+H_+k)*FH + gcol(cc, ln)];          // W0 h0-rows
    } else if (i < N0+N1) {
      int idx = i - N0;
      int cc = idx >> 15; int rem = idx & 32767;
      int kb = rem >> 8; int ln = (rem >> 2) & 63; int j = idx & 3;
      int k2 = kb*4 + j;                                  // 0..255 h0n, 256..511 h1
      wp1[idx] = W1[k2*FH + gcol(cc, ln)];
    } else if (i < N0+N1+N2) {
      int l = i - N0 - N1;
      int v = l >> 8, k = l & 255;
      dwT[l] = dW[k*V_ + v];
    } else {
      int cc2 = i - N0 - N1 - N2;
      b1p[cc2] = b1[gcol(cc2>>6, cc2&63)];
    }
  }
}

__global__ void prep_tok(const float* __restrict__ cemb, const float* __restrict__ W0,
                         float* __restrict__ ws) {
  __shared__ float ce[E_];
  float* TP = ws + OFF_TP;
  int v = blockIdx.x >> 2, q = blockIdx.x & 3;
  int tid = threadIdx.x;
  if (tid < E_) ce[tid] = cemb[v*E_ + tid];
  __syncthreads();
  int ccol = q*256 + tid;
  int G = gcol(ccol>>6, ccol&63);
  float acc = 0.f;
  for (int e = 0; e < E_; ++e) acc = fmaf(ce[e], W0[e*FH + G], acc);
  TP[v*FH + ccol] = acc;
}

__global__ void prep_clus(const int* __restrict__ clus, const float* __restrict__ clemb,
                          const float* __restrict__ W0, const float* __restrict__ b0,
                          float* __restrict__ ws) {
  __shared__ float ce[H_];
  float* CP = ws + OFF_CP;
  int b = blockIdx.x >> 2, q = blockIdx.x & 3;
  int tid = threadIdx.x;
  int cl = clus[b];
  ce[tid] = clemb[(long long)cl*H_ + tid];
  __syncthreads();
  int ccol = q*256 + tid;
  int G = gcol(ccol>>6, ccol&63);
  float acc = b0[G];
  for (int e = 0; e < H_; ++e) acc = fmaf(ce[e], W0[(E_+e)*FH + G], acc);
  CP[b*FH + ccol] = acc;
}

// rank-sort 256 rows by length, DESCENDING (deterministic tie-break by index).
__global__ void prep_sort(const int* __restrict__ lens, float* __restrict__ ws) {
  __shared__ int sl[B_];
  int* perm = (int*)(ws + OFF_PERM);
  const int i = threadIdx.x;
  sl[i] = lens[i];
  __syncthreads();
  const int li = sl[i];
  int rank = 0;
  for (int j = 0; j < B_; ++j) {
    const int lj = sl[j];
    rank += (lj > li) || (lj == li && j < i);
  }
  perm[rank] = i;
}

// ============ sync & staging primitives ============
// SLOW (agent) path: proven device-scope protocol. FAST (sc0) path:
// L1-bypass / XCD-L2-coherent — valid only when all 8 WGs of the group share
// one XCD (runtime-verified via HW_REG_XCC_ID; per-group uniform decision).

__device__ __forceinline__ void st64(float* p, float a, float b) {
  float2 t; t.x = a; t.y = b;
  __hip_atomic_store((ull*)p, __builtin_bit_cast(ull, t),
                     __ATOMIC_RELAXED, __HIP_MEMORY_SCOPE_AGENT);
}

__device__ __forceinline__ void st64_sc0(float* p, float a, float b) {
  float2 t; t.x = a; t.y = b;
  ull v = __builtin_bit_cast(ull, t);
  asm volatile("global_store_dwordx2 %0, %1, off sc0" :: "v"(p), "v"(v) : "memory");
}

__device__ __forceinline__ ull ld64(const void* p) {
  return __hip_atomic_load((const ull*)p, __ATOMIC_RELAXED, __HIP_MEMORY_SCOPE_AGENT);
}

// single 32b sc0 load with fused drain (load+wait in ONE asm stmt)
__device__ __forceinline__ unsigned ld32_sc0(const unsigned* p) {
  unsigned v;
  asm volatile("global_load_dword %0, %1, off sc0\n\t"
               "s_waitcnt vmcnt(0)"
               : "=v"(v) : "v"(p) : "memory");
  return v;
}

// flag publish: vmcnt(0) drains this wave's prior h-stores, then relaxed flag
// store at the matching scope. (Staging-load drain for the buffer-overwrite
// proof is provided by the compiler's vmcnt(0) before the per-step s_barrier.)
__device__ __forceinline__ void flag_set(unsigned* p, unsigned v) {
  asm volatile("s_waitcnt vmcnt(0)" ::: "memory");
  __hip_atomic_store(p, v, __ATOMIC_RELAXED, __HIP_MEMORY_SCOPE_AGENT);
}
__device__ __forceinline__ void flag_set_sc0(unsigned* p, unsigned v) {
  asm volatile("s_waitcnt vmcnt(0)" ::: "memory");
  asm volatile("global_store_dword %0, %1, off sc0" :: "v"(p), "v"(v) : "memory");
}

// PER-WAVE poll (all 8 waves): 16 flag lines — fA at c*32 (c=0..15), fB at
// c*32+16. lanes 0-31 cover fA lines, 32-63 fB lines.
__device__ __forceinline__ void spinAB(const unsigned* fgrp, int lane, unsigned tgt) {
  const unsigned* p = fgrp + (lane & 15)*32 + ((lane >> 5) << 4);
  unsigned v = __hip_atomic_load(p, __ATOMIC_RELAXED, __HIP_MEMORY_SCOPE_AGENT);
  while (!__all((int)(v >= tgt))) {
    __builtin_amdgcn_s_sleep(4);
    v = __hip_atomic_load(p, __ATOMIC_RELAXED, __HIP_MEMORY_SCOPE_AGENT);
  }
}
// fast variant: sc0 polls, tighter backoff; every 8th poll agent-scope safety net
__device__ __forceinline__ void spinAB_fast(const unsigned* fgrp, int lane, unsigned tgt) {
  const unsigned* p = fgrp + (lane & 15)*32 + ((lane >> 5) << 4);
  unsigned v = ld32_sc0(p);
  int it = 0;
  while (!__all((int)(v >= tgt))) {
    __builtin_amdgcn_s_sleep(2);
    ++it;
    v = (it & 7) ? ld32_sc0(p)
                 : __hip_atomic_load(p, __ATOMIC_RELAXED, __HIP_MEMORY_SCOPE_AGENT);
  }
}

// epilogue: fB lines only (agent — runs once, keep it safe)
__device__ __forceinline__ void spinB(const unsigned* fgrp, int lane, unsigned tgt) {
  const unsigned* p = fgrp + (lane & 15)*32 + 16;
  unsigned v = __hip_atomic_load(p, __ATOMIC_RELAXED, __HIP_MEMORY_SCOPE_AGENT);
  while (!__all((int)(v >= tgt))) {
    __builtin_amdgcn_s_sleep(4);
    v = __hip_atomic_load(p, __ATOMIC_RELAXED, __HIP_MEMORY_SCOPE_AGENT);
  }
}

__device__ __forceinline__ void lstm_gate(const f4 z, float& cc, float& hh, const bool upd) {
  float ci = sigm(z.x);
  float cj = tanh_(z.y);
  float cf = sigm(z.z + 1.f);
  float co = sigm(z.w);
  float cn = fmaf(cc, cf, ci*cj);
  float hn = tanh_(cn)*co;
  if (upd) { cc = cn; hh = hn; }
}

// ============ main persistent kernel ============
//
// R10 base + ONE structural change: WGPG 16->8, 512-thread WGs, 1 WG/CU.
//  - wave w = (ch = w>>2 column-half, kwin = w&3 k-window); ca = cc*2+ch is
//    the old packed column-slice. Each wave stages its OWN 64-k h-slice
//    (sibling ch-waves write identical values to the same LDS region —
//    benign; each wave depends only on its own writes).
//  - group step = max over 8 WGs (was 16); whole CU runs ONE group ->
//    deterministic matvec time (no cross-group SIMD contention jitter).
//  - za/zb [4 kwin][8 r'][128 col], single-buffered, protected by the same
//    flag-order proof (gate waves set their flag line AFTER their za/zb
//    reads; staging waits on all 16 lines).
//  - projection weights read directly from global dwT (L1/L2-resident);
//    frees 16.6KB LDS -> total 52KB fits.
//  - roles: waves 0/4 = L0 gates+publish (slice ca), 1/5 = L1, 2/6 = out.

__global__ __launch_bounds__(512, 2) void lstm_persist(
    const int* __restrict__ toks, const int* __restrict__ lens,
    const float* __restrict__ decB, float* __restrict__ ws, float* __restrict__ out)
{
  const int blk  = blockIdx.x;
  const int xcd  = blk & 7;
  const int j    = blk >> 3;                   // 0..31 within XCD
  const int cc   = j & 7;                      // column-WG 0..7
  const int loc  = j >> 3;                     // 0..3
  const int grp  = (xcd << 2) | loc;           // 0..31, XCD-local
  const int tid  = threadIdx.x;
  const int lane = tid & 63;
  const int wv   = tid >> 6;                   // 0..7
  const int ch   = wv >> 2;                    // column-half 0/1
  const int kwin = wv & 3;                     // k-window 0..3
  const int ca   = cc*2 + ch;                  // packed column-slice 0..15
  const int cof  = ca*64;

  // sorted-group id: loc*8 + xcd. loc0 = longest octile.
  const int sgrp  = (loc << 3) | xcd;
  const int rbase = sgrp*RPG;
  const int* perm = (const int*)(ws + OFF_PERM);

  float* ht0 = ws + OFF_HT0;
  float* ht1 = ws + OFF_HT1;
  unsigned* fgrp = (unsigned*)(ws + OFF_BAR) + grp*1024;
  const float* TP   = ws + OFF_TP;
  const float* CP   = ws + OFF_CP;
  const float* wp0c = ws + OFF_WP0 + ca*(64*64*4);
  const float* wp1c = ws + OFF_WP1 + ca*(128*64*4);
  const float* dwT  = ws + OFF_DWT;
  const float* b1p  = ws + OFF_B1;

  __shared__ __align__(16) float h0s[4*512];    // [kwin][64k][8 r'] (dup-written)
  __shared__ __align__(16) float h1s[4*512];
  __shared__ __align__(16) float za[4][8][128]; // z0 partials [kwin][r'][col]
  __shared__ __align__(16) float zb[4][8][128]; // z1 partials
  __shared__ float pred[2][4][2][64];           // proj partials [buf][kwin][ch][lane]
  __shared__ unsigned fastSh;

  // ---- runtime XCD-colocation check (agent scope; all 256 WGs co-resident)
  unsigned xcc;
  asm volatile("s_getreg_b32 %0, hwreg(HW_REG_XCC_ID)" : "=s"(xcc));
  if (tid == 0)
    __hip_atomic_store(fgrp + 512 + cc, xcc + 1u, __ATOMIC_RELAXED, __HIP_MEMORY_SCOPE_AGENT);
  if (wv == 0) {
    const unsigned* p = fgrp + 512 + (lane & 7);
    unsigned v = __hip_atomic_load(p, __ATOMIC_RELAXED, __HIP_MEMORY_SCOPE_AGENT);
    while (!__all((int)(v != 0u))) {
      __builtin_amdgcn_s_sleep(8);
      v = __hip_atomic_load(p, __ATOMIC_RELAXED, __HIP_MEMORY_SCOPE_AGENT);
    }
    const bool same = __all((int)(v == xcc + 1u));
    if (lane == 0) fastSh = same ? 1u : 0u;
  }

  // ---- group max length (all lanes), through the permutation ----
  int Lg = lens[perm[rbase + (lane & 7)]];
  Lg = max(Lg, __shfl_xor(Lg, 1));
  Lg = max(Lg, __shfl_xor(Lg, 2));
  Lg = max(Lg, __shfl_xor(Lg, 4));

  // ---- gate-lane constants (waves 0/4 = L0, 1/5 = L1 for slice ca) ----
  const int gu = lane & 15, q = lane >> 4;   // unit 0..15, q 0..3 (rows q, q+4)
  const int rowA = perm[rbase + q], rowB = perm[rbase + q + 4];
  const int lenA = lens[rowA], lenB = lens[rowB];
  const int* tokApt = toks + rowA*T_;
  const int* tokBpt = toks + rowB*T_;
  const f4 cpA = *(const f4*)(CP + rowA*FH + cof + gu*4);
  const f4 cpB = *(const f4*)(CP + rowB*FH + cof + gu*4);
  const f4 b1v = *(const f4*)(b1p + cof + gu*4);
  const int puboff = grp*HTG + (ca*16 + gu)*8 + q*2;   // r' = 2q (+1)
  float c0A = 0.f, h0A = 0.f, c0B = 0.f, h0B = 0.f;    // L0 state (waves 0/4)
  float c1A = 0.f, h1A = 0.f, c1B = 0.f, h1B = 0.f;    // L1 state (waves 1/5)

  // ---- projection constants ----
  const int pm = lane >> 3, pv = lane & 7;            // row 0..7, vocab-col 0..7
  const int prm = (pm < 4) ? pm*2 : (pm-4)*2 + 1;     // r' of row pm
  const int prow = perm[rbase + pm];
  const int plen = lens[prow];
  const float decb = decB[ca*8 + pv];
  float* outp = out + (size_t)prow*T_*V_ + ca*8 + pv;
  const float* dwRow = dwT + (ca*8 + pv)*H_;          // this lane's vocab row

  __syncthreads();   // fastSh decided
  const bool fast = (fastSh != 0u);

  // ---- prologue: H0(0) from TP+CP; H1(-1)=0 via pre-zeroed ws ----
  if ((wv & 3) == 0) {
    f4 zAv = *(const f4*)(TP + tokApt[0]*FH + cof + gu*4) + cpA;
    f4 zBv = *(const f4*)(TP + tokBpt[0]*FH + cof + gu*4) + cpB;
    lstm_gate(zAv, c0A, h0A, 0 < lenA);
    lstm_gate(zBv, c0B, h0B, 0 < lenB);
    if (fast) st64_sc0(ht0 + puboff, h0A, h0B);
    else      st64(ht0 + puboff, h0A, h0B);       // buf0
    if (lane == 0) {
      if (fast) flag_set_sc0(fgrp + ca*32, 1u);
      else      flag_set(fgrp + ca*32, 1u);
    }
  } else if ((wv & 3) == 1) {
    if (lane == 0) {
      if (fast) flag_set_sc0(fgrp + ca*32 + 16, 1u);
      else      flag_set(fgrp + ca*32 + 16, 1u);   // h1 buf0 pre-zeroed
    }
  }

  for (int t = 0; t < Lg; ++t) {
    const int buf = t & 1;

    // TP prefetch for next-step z0 (in flight across the spin)
    f4 tpA = {0,0,0,0}, tpB = {0,0,0,0};
    if ((wv & 3) == 0 && t + 1 < Lg) {
      tpA = *(const f4*)(TP + tokApt[t+1]*FH + cof + gu*4);
      tpB = *(const f4*)(TP + tokBpt[t+1]*FH + cof + gu*4);
    }

    // ---- per-wave spin: {H0(t), H1(t-1)} both ready (no barrier after) ----
    if (fast) spinAB_fast(fgrp, lane, (unsigned)(t + 1));
    else      spinAB(fgrp, lane, (unsigned)(t + 1));
    __atomic_signal_fence(__ATOMIC_SEQ_CST);

    // ---- stage OWN 64-k slice (sibling ch-wave duplicates: benign) ----
    {
      const float* s0 = ht0 + buf*GST + grp*HTG + kwin*512 + lane*8;
      const float* s1 = ht1 + buf*GST + grp*HTG + kwin*512 + lane*8;
      ull a0, a1, a2, a3, c0, c1, c2, c3;
      if (fast) {
        asm volatile(
          "global_load_dwordx2 %0, %8, off sc0\n\t"
          "global_load_dwordx2 %1, %8, off offset:8 sc0\n\t"
          "global_load_dwordx2 %2, %8, off offset:16 sc0\n\t"
          "global_load_dwordx2 %3, %8, off offset:24 sc0\n\t"
          "global_load_dwordx2 %4, %9, off sc0\n\t"
          "global_load_dwordx2 %5, %9, off offset:8 sc0\n\t"
          "global_load_dwordx2 %6, %9, off offset:16 sc0\n\t"
          "global_load_dwordx2 %7, %9, off offset:24 sc0\n\t"
          "s_waitcnt vmcnt(0)"
          : "=&v"(a0), "=&v"(a1), "=&v"(a2), "=&v"(a3),
            "=&v"(c0), "=&v"(c1), "=&v"(c2), "=&v"(c3)
          : "v"(s0), "v"(s1)
          : "memory");
      } else {
        a0 = ld64(s0);   a1 = ld64(s0+2); a2 = ld64(s0+4); a3 = ld64(s0+6);
        c0 = ld64(s1);   c1 = ld64(s1+2); c2 = ld64(s1+4); c3 = ld64(s1+6);
      }
      float* d0 = h0s + kwin*512 + lane*8;
      float* d1 = h1s + kwin*512 + lane*8;
      *(ull*)(d0)   = a0; *(ull*)(d0+2) = a1; *(ull*)(d0+4) = a2; *(ull*)(d0+6) = a3;
      *(ull*)(d1)   = c0; *(ull*)(d1+2) = c1; *(ull*)(d1+4) = c2; *(ull*)(d1+6) = c3;
    }

    // ---- fused matvec over this wave's k-window, slice ca:
    //      A0 = W0h*h0; A1 = W1lo*h0 + W1up*h1 (rows in r' order) ----
    f4 A0l = {0,0,0,0}, A0h = {0,0,0,0}, A1l = {0,0,0,0}, A1h = {0,0,0,0};
    #pragma unroll 2
    for (int b = 0; b < 16; ++b) {
      const int kb = kwin*16 + b;
      const f4 w0 = *(const f4*)(wp0c + kb*256 + lane*4);
      const f4 wl = *(const f4*)(wp1c + kb*256 + lane*4);
      const f4 wu = *(const f4*)(wp1c + (64 + kb)*256 + lane*4);
      #pragma unroll
      for (int jj = 0; jj < 4; ++jj) {
        const int kl = b*4 + jj;                 // k within window
        const float* hb0 = h0s + kwin*512 + kl*8;
        const float* hb1 = h1s + kwin*512 + kl*8;
        const f4 h0lo = *(const f4*)(hb0);
        const f4 h0hi = *(const f4*)(hb0 + 4);
        const f4 h1lo = *(const f4*)(hb1);
        const f4 h1hi = *(const f4*)(hb1 + 4);
        const float w0j = w0[jj], wlj = wl[jj], wuj = wu[jj];
        A0l += w0j * h0lo;  A0h += w0j * h0hi;
        A1l += wlj * h0lo + wuj * h1lo;
        A1h += wlj * h0hi + wuj * h1hi;
      }
    }

    // ---- projection partial: this wave's k-window, vocab 8-set (ca,pv) ----
    float pacc = 0.f;
    {
      const float* wrow = dwRow + kwin*64;
      #pragma unroll 4
      for (int k2 = 0; k2 < 64; k2 += 4) {
        const f4 w4 = *(const f4*)(wrow + k2);
        pacc = fmaf(h1s[kwin*512 + (k2  )*8 + prm], w4.x, pacc);
        pacc = fmaf(h1s[kwin*512 + (k2+1)*8 + prm], w4.y, pacc);
        pacc = fmaf(h1s[kwin*512 + (k2+2)*8 + prm], w4.z, pacc);
        pacc = fmaf(h1s[kwin*512 + (k2+3)*8 + prm], w4.w, pacc);
      }
    }

    #pragma unroll
    for (int r = 0; r < 4; ++r) {
      za[kwin][r][ch*64 + lane]     = A0l[r];
      za[kwin][4 + r][ch*64 + lane] = A0h[r];
      zb[kwin][r][ch*64 + lane]     = A1l[r];
      zb[kwin][4 + r][ch*64 + lane] = A1h[r];
    }
    pred[buf][kwin][ch][lane] = pacc;
    __syncthreads();      // the ONLY barrier per step (drains vmcnt too)

    const int cb = ch*64;
    if ((wv & 3) == 0) {
      // L0 gates for slice ca -> H0(t+1), publish to buf^1
      if (t + 1 < Lg) {
        f4 zA = *(const f4*)&za[0][q*2][cb + gu*4];
        zA += *(const f4*)&za[1][q*2][cb + gu*4];
        zA += *(const f4*)&za[2][q*2][cb + gu*4];
        zA += *(const f4*)&za[3][q*2][cb + gu*4];
        f4 zB = *(const f4*)&za[0][q*2+1][cb + gu*4];
        zB += *(const f4*)&za[1][q*2+1][cb + gu*4];
        zB += *(const f4*)&za[2][q*2+1][cb + gu*4];
        zB += *(const f4*)&za[3][q*2+1][cb + gu*4];
        zA += tpA + cpA;
        zB += tpB + cpB;
        lstm_gate(zA, c0A, h0A, (t+1) < lenA);
        lstm_gate(zB, c0B, h0B, (t+1) < lenB);
        float* pb = ht0 + (buf^1)*GST + puboff;
        if (fast) st64_sc0(pb, h0A, h0B);
        else      st64(pb, h0A, h0B);
        if (lane == 0) {
          if (fast) flag_set_sc0(fgrp + ca*32, (unsigned)(t + 2));
          else      flag_set(fgrp + ca*32, (unsigned)(t + 2));
        }
      }
    } else if ((wv & 3) == 1) {
      // L1 gates for slice ca -> H1(t), publish to buf^1
      f4 zA = *(const f4*)&zb[0][q*2][cb + gu*4];
      zA += *(const f4*)&zb[1][q*2][cb + gu*4];
      zA += *(const f4*)&zb[2][q*2][cb + gu*4];
      zA += *(const f4*)&zb[3][q*2][cb + gu*4];
      f4 zB = *(const f4*)&zb[0][q*2+1][cb + gu*4];
      zB += *(const f4*)&zb[1][q*2+1][cb + gu*4];
      zB += *(const f4*)&zb[2][q*2+1][cb + gu*4];
      zB += *(const f4*)&zb[3][q*2+1][cb + gu*4];
      zA += b1v;
      zB += b1v;
      lstm_gate(zA, c1A, h1A, t < lenA);
      lstm_gate(zB, c1B, h1B, t < lenB);
      float* pb = ht1 + (buf^1)*GST + puboff;
      if (fast) st64_sc0(pb, h1A, h1B);
      else      st64(pb, h1A, h1B);
      if (lane == 0) {
        if (fast) flag_set_sc0(fgrp + ca*32 + 16, (unsigned)(t + 2));
        else      flag_set(fgrp + ca*32 + 16, (unsigned)(t + 2));
      }
    } else if ((wv & 3) == 2) {
      // out(t-1) for vocab half ch from pred[buf] (computed from H1(t-1))
      if (t > 0) {
        float tot = pred[buf][0][ch][lane] + pred[buf][1][ch][lane]
                  + pred[buf][2][ch][lane] + pred[buf][3][ch][lane] + decb;
        if (t - 1 < plen) outp[(size_t)(t-1)*V_] = tot;
      }
    }
  }

  // ---- epilogue: out(Lg-1) from H1(Lg-1) in buf (Lg&1), fB reaches Lg+1 ----
  spinB(fgrp, lane, (unsigned)(Lg + 1));
  __atomic_signal_fence(__ATOMIC_SEQ_CST);
  {
    const float* s1 = ht1 + (size_t)(Lg & 1)*GST + grp*HTG + kwin*512 + lane*8;
    ull b0 = ld64(s1),   b1 = ld64(s1+2);
    ull b2 = ld64(s1+4), b3 = ld64(s1+6);
    float* d1 = h1s + kwin*512 + lane*8;
    *(ull*)(d1)   = b0; *(ull*)(d1+2) = b1;
    *(ull*)(d1+4) = b2; *(ull*)(d1+6) = b3;
  }
  {
    float pacc = 0.f;
    const float* wrow = dwRow + kwin*64;
    #pragma unroll 4
    for (int k2 = 0; k2 < 64; k2 += 4) {
      const f4 w4 = *(const f4*)(wrow + k2);
      pacc = fmaf(h1s[kwin*512 + (k2  )*8 + prm], w4.x, pacc);
      pacc = fmaf(h1s[kwin*512 + (k2+1)*8 + prm], w4.y, pacc);
      pacc = fmaf(h1s[kwin*512 + (k2+2)*8 + prm], w4.z, pacc);
      pacc = fmaf(h1s[kwin*512 + (k2+3)*8 + prm], w4.w, pacc);
    }
    pred[Lg & 1][kwin][ch][lane] = pacc;
  }
  __syncthreads();
  if ((wv & 3) == 2) {
    float tot = pred[Lg & 1][0][ch][lane] + pred[Lg & 1][1][ch][lane]
              + pred[Lg & 1][2][ch][lane] + pred[Lg & 1][3][ch][lane] + decb;
    if (Lg - 1 < plen) outp[(size_t)(Lg-1)*V_] = tot;
  }
}

// ============ launch ============

extern "C" void kernel_launch(void* const* d_in, const int* in_sizes, int n_in,
                              void* d_out, int out_size, void* d_ws, size_t ws_size,
                              hipStream_t stream) {
  const int*   toks  = (const int*)d_in[0];
  const int*   lens  = (const int*)d_in[1];
  const int*   clus  = (const int*)d_in[2];
  const float* cemb  = (const float*)d_in[3];
  const float* clemb = (const float*)d_in[4];
  const float* W0    = (const float*)d_in[5];
  const float* b0    = (const float*)d_in[6];
  const float* W1    = (const float*)d_in[7];
  const float* b1    = (const float*)d_in[8];
  const float* dW    = (const float*)d_in[9];
  const float* decB  = (const float*)d_in[10];
  float* out = (float*)d_out;
  float* ws  = (float*)d_ws;

  // zero output (masked positions must be exactly 0), h buffers (H1(-1)=0),
  // and the flag block (incl. xcc slots)
  hipMemsetAsync(out, 0, (size_t)B_*T_*V_*sizeof(float), stream);
  hipMemsetAsync(ws, 0, (size_t)(OFF_BAR + BARSZ)*sizeof(float), stream);

  prep_pack<<<1024, 256, 0, stream>>>(W0, W1, dW, b1, ws);
  prep_tok <<<V_*4, 256, 0, stream>>>(cemb, W0, ws);
  prep_clus<<<B_*4, 256, 0, stream>>>(clus, clemb, W0, b0, ws);
  prep_sort<<<1, 256, 0, stream>>>(lens, ws);
  lstm_persist<<<NWG, 512, 0, stream>>>(toks, lens, decB, ws, out);
}

// Round 13
// 5995.421 us; speedup vs baseline: 1.0527x; 1.0527x over previous
//
#include <hip/hip_runtime.h>

#define B_ 256
#define T_ 512
#define V_ 128
#define E_ 128
#define H_ 256
#define FH 1024

#define GROUPS 32
#define RPG 8      // batch rows per group
#define CWG 16     // column-WGs per group
#define NWG (GROUPS*CWG)   // 512 = 2 blocks/CU

#define HTG 2048   // floats: one group's h, one layer, one buffer ([16c][16gu][8 r'])
#define GST (GROUPS*HTG)   // 65536

typedef float f4 __attribute__((ext_vector_type(4)));
typedef unsigned long long ull;

// ---- workspace layout (float offsets) ----
#define OFF_HT0  0                              // h0 [2buf][grp][c][gu][r']
#define OFF_HT1  (OFF_HT0 + 2*GST)
#define OFF_BAR  (OFF_HT1 + 2*GST)              // 32 groups * 1024 uints (4KB/grp)
#define BARSZ    (GROUPS*1024)                  // fA_c at [c*32], fB_c at [c*32+16]; xcc at [512+c]
#define OFF_TP   (OFF_BAR + BARSZ)              // TokProj [V][1024] packed
#define OFF_CP   (OFF_TP + V_*FH)               // ClusProj [B][1024] packed (+b0)
#define OFF_WP0  (OFF_CP + B_*FH)               // W0h x4-packed [16c][64kb][64lane][4j]
#define OFF_WP1  (OFF_WP0 + CWG*64*64*4)        // W1  x4-packed [16c][128kb][64lane][4j]
#define OFF_DWT  (OFF_WP1 + CWG*128*64*4)       // decoderW^T [128v][256k]
#define OFF_B1   (OFF_DWT + V_*H_)              // b1 packed [1024]
#define OFF_PERM (OFF_B1 + FH)                  // row permutation [256] (ints)

// packed column order: local col = u*4+g  ->  global z-col G = g*256 + c*16 + u
__device__ __forceinline__ int gcol(int c, int col) {
  int u = col >> 2, g = col & 3;
  return g*256 + c*16 + u;
}

__device__ __forceinline__ float sigm(float x){ return 1.f/(1.f+__expf(-x)); }
__device__ __forceinline__ float tanh_(float x){ return 1.f - 2.f/(1.f+__expf(2.f*x)); }

// ============ prep kernels ============

__global__ void prep_pack(const float* __restrict__ W0, const float* __restrict__ W1,
                          const float* __restrict__ dW, const float* __restrict__ b1,
                          float* __restrict__ ws) {
  float* wp0 = ws + OFF_WP0; float* wp1 = ws + OFF_WP1;
  float* dwT = ws + OFF_DWT; float* b1p = ws + OFF_B1;
  const int N0 = CWG*64*64*4;     // 262144
  const int N1 = CWG*128*64*4;    // 524288
  const int N2 = V_*H_;           // 32768
  const int N3 = FH;              // 1024
  const int total = N0+N1+N2+N3;
  for (int i = blockIdx.x*blockDim.x + threadIdx.x; i < total; i += gridDim.x*blockDim.x) {
    if (i < N0) {
      int cc = i >> 14; int rem = i & 16383;
      int kb = rem >> 8; int ln = (rem >> 2) & 63; int j = i & 3;
      int k = kb*4 + j;
      wp0[i] = W0[(E_+H_+k)*FH + gcol(cc, ln)];          // W0 h0-rows
    } else if (i < N0+N1) {
      int idx = i - N0;
      int cc = idx >> 15; int rem = idx & 32767;
      int kb = rem >> 8; int ln = (rem >> 2) & 63; int j = idx & 3;
      int k2 = kb*4 + j;                                  // 0..255 h0n, 256..511 h1
      wp1[idx] = W1[k2*FH + gcol(cc, ln)];
    } else if (i < N0+N1+N2) {
      int l = i - N0 - N1;
      int v = l >> 8, k = l & 255;
      dwT[l] = dW[k*V_ + v];
    } else {
      int cc2 = i - N0 - N1 - N2;
      b1p[cc2] = b1[gcol(cc2>>6, cc2&63)];
    }
  }
}

__global__ void prep_tok(const float* __restrict__ cemb, const float* __restrict__ W0,
                         float* __restrict__ ws) {
  __shared__ float ce[E_];
  float* TP = ws + OFF_TP;
  int v = blockIdx.x >> 2, q = blockIdx.x & 3;
  int tid = threadIdx.x;
  if (tid < E_) ce[tid] = cemb[v*E_ + tid];
  __syncthreads();
  int ccol = q*256 + tid;
  int G = gcol(ccol>>6, ccol&63);
  float acc = 0.f;
  for (int e = 0; e < E_; ++e) acc = fmaf(ce[e], W0[e*FH + G], acc);
  TP[v*FH + ccol] = acc;
}

__global__ void prep_clus(const int* __restrict__ clus, const float* __restrict__ clemb,
                          const float* __restrict__ W0, const float* __restrict__ b0,
                          float* __restrict__ ws) {
  __shared__ float ce[H_];
  float* CP = ws + OFF_CP;
  int b = blockIdx.x >> 2, q = blockIdx.x & 3;
  int tid = threadIdx.x;
  int cl = clus[b];
  ce[tid] = clemb[(long long)cl*H_ + tid];
  __syncthreads();
  int ccol = q*256 + tid;
  int G = gcol(ccol>>6, ccol&63);
  float acc = b0[G];
  for (int e = 0; e < H_; ++e) acc = fmaf(ce[e], W0[(E_+e)*FH + G], acc);
  CP[b*FH + ccol] = acc;
}

// rank-sort 256 rows by length, DESCENDING (deterministic tie-break by index).
__global__ void prep_sort(const int* __restrict__ lens, float* __restrict__ ws) {
  __shared__ int sl[B_];
  int* perm = (int*)(ws + OFF_PERM);
  const int i = threadIdx.x;
  sl[i] = lens[i];
  __syncthreads();
  const int li = sl[i];
  int rank = 0;
  for (int j = 0; j < B_; ++j) {
    const int lj = sl[j];
    rank += (lj > li) || (lj == li && j < i);
  }
  perm[rank] = i;
}

// ============ sync & staging primitives ============
// SLOW (agent) path: proven device-scope protocol. FAST (sc0) path:
// L1-bypass / XCD-L2-coherent — valid only when all 16 WGs of the group share
// one XCD (runtime-verified via HW_REG_XCC_ID; per-group uniform decision).

__device__ __forceinline__ void st64(float* p, float a, float b) {
  float2 t; t.x = a; t.y = b;
  __hip_atomic_store((ull*)p, __builtin_bit_cast(ull, t),
                     __ATOMIC_RELAXED, __HIP_MEMORY_SCOPE_AGENT);
}

__device__ __forceinline__ void st64_sc0(float* p, float a, float b) {
  float2 t; t.x = a; t.y = b;
  ull v = __builtin_bit_cast(ull, t);
  asm volatile("global_store_dwordx2 %0, %1, off sc0" :: "v"(p), "v"(v) : "memory");
}

__device__ __forceinline__ ull ld64(const void* p) {
  return __hip_atomic_load((const ull*)p, __ATOMIC_RELAXED, __HIP_MEMORY_SCOPE_AGENT);
}

// single 32b sc0 load with fused drain (load+wait in ONE asm stmt)
__device__ __forceinline__ unsigned ld32_sc0(const unsigned* p) {
  unsigned v;
  asm volatile("global_load_dword %0, %1, off sc0\n\t"
               "s_waitcnt vmcnt(0)"
               : "=v"(v) : "v"(p) : "memory");
  return v;
}

// flag publish: vmcnt(0) drains this wave's prior h-stores (and any pending
// loads), then relaxed flag store at the matching scope.
__device__ __forceinline__ void flag_set(unsigned* p, unsigned v) {
  asm volatile("s_waitcnt vmcnt(0)" ::: "memory");
  __hip_atomic_store(p, v, __ATOMIC_RELAXED, __HIP_MEMORY_SCOPE_AGENT);
}
__device__ __forceinline__ void flag_set_sc0(unsigned* p, unsigned v) {
  asm volatile("s_waitcnt vmcnt(0)" ::: "memory");
  asm volatile("global_store_dword %0, %1, off sc0" :: "v"(p), "v"(v) : "memory");
}

// PER-WAVE polls. Flags: one 64B line per (c,type): fA at c*32, fB at c*32+16.
// All 64 lanes cover the 16 lines of one type via lane&15 (redundant 4x).
__device__ __forceinline__ void spinA(const unsigned* fgrp, int lane, unsigned tgt) {
  const unsigned* p = fgrp + (lane & 15)*32;
  unsigned v = __hip_atomic_load(p, __ATOMIC_RELAXED, __HIP_MEMORY_SCOPE_AGENT);
  while (!__all((int)(v >= tgt))) {
    __builtin_amdgcn_s_sleep(4);
    v = __hip_atomic_load(p, __ATOMIC_RELAXED, __HIP_MEMORY_SCOPE_AGENT);
  }
}
__device__ __forceinline__ void spinA_fast(const unsigned* fgrp, int lane, unsigned tgt) {
  const unsigned* p = fgrp + (lane & 15)*32;
  unsigned v = ld32_sc0(p);
  int it = 0;
  while (!__all((int)(v >= tgt))) {
    __builtin_amdgcn_s_sleep(2);
    ++it;
    v = (it & 7) ? ld32_sc0(p)
                 : __hip_atomic_load(p, __ATOMIC_RELAXED, __HIP_MEMORY_SCOPE_AGENT);
  }
}
__device__ __forceinline__ void spinB(const unsigned* fgrp, int lane, unsigned tgt) {
  const unsigned* p = fgrp + (lane & 15)*32 + 16;
  unsigned v = __hip_atomic_load(p, __ATOMIC_RELAXED, __HIP_MEMORY_SCOPE_AGENT);
  while (!__all((int)(v >= tgt))) {
    __builtin_amdgcn_s_sleep(4);
    v = __hip_atomic_load(p, __ATOMIC_RELAXED, __HIP_MEMORY_SCOPE_AGENT);
  }
}
__device__ __forceinline__ void spinB_fast(const unsigned* fgrp, int lane, unsigned tgt) {
  const unsigned* p = fgrp + (lane & 15)*32 + 16;
  unsigned v = ld32_sc0(p);
  int it = 0;
  while (!__all((int)(v >= tgt))) {
    __builtin_amdgcn_s_sleep(2);
    ++it;
    v = (it & 7) ? ld32_sc0(p)
                 : __hip_atomic_load(p, __ATOMIC_RELAXED, __HIP_MEMORY_SCOPE_AGENT);
  }
}

__device__ __forceinline__ void lstm_gate(const f4 z, float& cc, float& hh, const bool upd) {
  float ci = sigm(z.x);
  float cj = tanh_(z.y);
  float cf = sigm(z.z + 1.f);
  float co = sigm(z.w);
  float cn = fmaf(cc, cf, ci*cj);
  float hn = tanh_(cn)*co;
  if (upd) { cc = cn; hh = hn; }
}

// ============ main persistent kernel ============
//
// R10 base (per-wave spin, single barrier, sc0 fast path, sorted groups,
// GROUPS=32 / 2 blocks/CU) + ONE structural change: EARLY h0-PUBLISH.
// Step t:
//  phase A: spinA(t+1) -> stage h0 (wave-private, drained) -> a0 matvec ->
//    za writes -> za-counter bump (1 LDS atomic/wave). Wave0 spins the
//    counter (proves ALL waves staged h0(t) + wrote za), reduces z0, gates
//    L0, publishes h0(t+1) + fA=t+2 MID-STEP.
//  phase B: spinB(t+1) -> stage h1 -> a1+proj matvec -> zb/pred -> barrier
//    -> wave1: L1 gates + publish h1(t) + fB=t+2; wave2: out(t-1).
// The h0 inter-WG loop no longer contains phase B; fB certification is
// unchanged (set post-barrier, which drains all waves' loads).
// za overwrite at t+1 gated by own fA>=t+2 (set after wave0's za reads);
// zb via fB likewise; pred double-buffered by t&1.

__global__ __launch_bounds__(256, 2) void lstm_persist(
    const int* __restrict__ toks, const int* __restrict__ lens,
    const float* __restrict__ decB, float* __restrict__ ws, float* __restrict__ out)
{
  const int blk  = blockIdx.x;
  const int xcd  = blk & 7;
  const int j    = blk >> 3;                               // 0..63 within XCD
  const int grp  = (xcd << 2) | ((j & 1) << 1) | (j >> 5); // 0..31, XCD-local
  const int c    = (j >> 1) & 15;                          // column-WG 0..15
  const int tid  = threadIdx.x;
  const int lane = tid & 63;
  const int wv   = tid >> 6;
  const int cof  = c*64;

  // sorted-group id: loc*8 + xcd  (loc = grp&3). loc0 = longest octile.
  const int sgrp  = ((grp & 3) << 3) | (grp >> 2);
  const int rbase = sgrp*RPG;
  const int* perm = (const int*)(ws + OFF_PERM);

  float* ht0 = ws + OFF_HT0;
  float* ht1 = ws + OFF_HT1;
  unsigned* fgrp = (unsigned*)(ws + OFF_BAR) + grp*1024;
  const float* TP   = ws + OFF_TP;
  const float* CP   = ws + OFF_CP;
  const float* wp0c = ws + OFF_WP0 + c*(64*64*4);
  const float* wp1c = ws + OFF_WP1 + c*(128*64*4);
  const float* dwT  = ws + OFF_DWT;
  const float* b1p  = ws + OFF_B1;

  __shared__ __align__(16) float h0s[2048];     // [256k][8 r'], wave-private slices
  __shared__ __align__(16) float h1s[2048];
  __shared__ __align__(16) float za[4][8][64];  // z0 partials (flag-protected)
  __shared__ __align__(16) float zb[4][8][64];  // z1 partials (flag-protected)
  __shared__ float ldsW[8][260];                // decoderW slice [v][k], padded
  __shared__ float pred[2][4][64];              // proj partials, dbuf by t&1
  __shared__ unsigned fastSh;
  __shared__ unsigned zaCtr;                    // za-arrival counter (monotone)

  if (tid == 0) zaCtr = 0u;

  // stage decoder weight slice (v = c*8 .. c*8+7)
  for (int i = tid; i < 8*H_; i += 256)
    ldsW[i>>8][i&255] = dwT[(c*8 + (i>>8))*H_ + (i&255)];

  // ---- runtime XCD-colocation check (agent scope; all 512 WGs co-resident)
  unsigned xcc;
  asm volatile("s_getreg_b32 %0, hwreg(HW_REG_XCC_ID)" : "=s"(xcc));
  if (tid == 0)
    __hip_atomic_store(fgrp + 512 + c, xcc + 1u, __ATOMIC_RELAXED, __HIP_MEMORY_SCOPE_AGENT);
  if (wv == 0) {
    const unsigned* p = fgrp + 512 + (lane & 15);
    unsigned v = __hip_atomic_load(p, __ATOMIC_RELAXED, __HIP_MEMORY_SCOPE_AGENT);
    while (!__all((int)(v != 0u))) {
      __builtin_amdgcn_s_sleep(8);
      v = __hip_atomic_load(p, __ATOMIC_RELAXED, __HIP_MEMORY_SCOPE_AGENT);
    }
    const bool same = __all((int)(v == xcc + 1u));
    if (lane == 0) fastSh = same ? 1u : 0u;
  }

  // ---- group max length (all lanes), through the permutation ----
  int Lg = lens[perm[rbase + (lane & 7)]];
  Lg = max(Lg, __shfl_xor(Lg, 1));
  Lg = max(Lg, __shfl_xor(Lg, 2));
  Lg = max(Lg, __shfl_xor(Lg, 4));

  // ---- gate-lane constants (wave0 = layer0, wave1 = layer1) ----
  const int gu = lane & 15, q = lane >> 4;   // unit 0..15, q 0..3 (rows q, q+4)
  const int rowA = perm[rbase + q], rowB = perm[rbase + q + 4];
  const int lenA = lens[rowA], lenB = lens[rowB];
  const int* tokApt = toks + rowA*T_;
  const int* tokBpt = toks + rowB*T_;
  const f4 cpA = *(const f4*)(CP + rowA*FH + cof + gu*4);
  const f4 cpB = *(const f4*)(CP + rowB*FH + cof + gu*4);
  const f4 b1v = *(const f4*)(b1p + cof + gu*4);
  const int puboff = grp*HTG + (c*16 + gu)*8 + q*2;   // r' = 2q (+1)
  float c0A = 0.f, h0A = 0.f, c0B = 0.f, h0B = 0.f;   // wave0 L0 state
  float c1A = 0.f, h1A = 0.f, c1B = 0.f, h1B = 0.f;   // wave1 L1 state

  // ---- projection constants ----
  const int pm = lane >> 3, pv = lane & 7;            // row 0..7, vocab-col 0..7
  const int prm = (pm < 4) ? pm*2 : (pm-4)*2 + 1;     // r' of row pm
  const int prow = perm[rbase + pm];
  const int plen = lens[prow];
  const float decb = decB[c*8 + pv];
  float* outp = out + (size_t)prow*T_*V_ + c*8 + pv;

  __syncthreads();   // ldsW staged + fastSh + zaCtr init
  const bool fast = (fastSh != 0u);

  // ---- prologue: H0(0) from TP+CP; H1(-1)=0 via pre-zeroed ws ----
  if (wv == 0) {
    f4 zAv = *(const f4*)(TP + tokApt[0]*FH + cof + gu*4) + cpA;
    f4 zBv = *(const f4*)(TP + tokBpt[0]*FH + cof + gu*4) + cpB;
    lstm_gate(zAv, c0A, h0A, 0 < lenA);
    lstm_gate(zBv, c0B, h0B, 0 < lenB);
    if (fast) st64_sc0(ht0 + puboff, h0A, h0B);
    else      st64(ht0 + puboff, h0A, h0B);       // buf0
    if (lane == 0) {
      if (fast) flag_set_sc0(fgrp + c*32, 1u);
      else      flag_set(fgrp + c*32, 1u);
    }
  } else if (wv == 1) {
    if (lane == 0) {
      if (fast) flag_set_sc0(fgrp + c*32 + 16, 1u);
      else      flag_set(fgrp + c*32 + 16, 1u);   // h1 buf0 pre-zeroed
    }
  }

  for (int t = 0; t < Lg; ++t) {
    const int buf = t & 1;

    // TP prefetch for next-step z0 (in flight across the spin)
    f4 tpA = {0,0,0,0}, tpB = {0,0,0,0};
    if (wv == 0 && t + 1 < Lg) {
      tpA = *(const f4*)(TP + tokApt[t+1]*FH + cof + gu*4);
      tpB = *(const f4*)(TP + tokBpt[t+1]*FH + cof + gu*4);
    }

    // ======== phase A: h0-dependent work ========
    if (fast) spinA_fast(fgrp, lane, (unsigned)(t + 1));
    else      spinA(fgrp, lane, (unsigned)(t + 1));
    __atomic_signal_fence(__ATOMIC_SEQ_CST);

    // stage OWN 64-k h0 slice (loads DRAINED before LDS writes)
    {
      const float* s0 = ht0 + buf*GST + grp*HTG + wv*512 + lane*8;
      ull a0, a1, a2, a3;
      if (fast) {
        asm volatile(
          "global_load_dwordx2 %0, %4, off sc0\n\t"
          "global_load_dwordx2 %1, %4, off offset:8 sc0\n\t"
          "global_load_dwordx2 %2, %4, off offset:16 sc0\n\t"
          "global_load_dwordx2 %3, %4, off offset:24 sc0\n\t"
          "s_waitcnt vmcnt(0)"
          : "=&v"(a0), "=&v"(a1), "=&v"(a2), "=&v"(a3)
          : "v"(s0)
          : "memory");
      } else {
        a0 = ld64(s0); a1 = ld64(s0+2); a2 = ld64(s0+4); a3 = ld64(s0+6);
      }
      float* d0 = h0s + wv*512 + lane*8;
      *(ull*)(d0)   = a0; *(ull*)(d0+2) = a1; *(ull*)(d0+4) = a2; *(ull*)(d0+6) = a3;
    }

    // a0 matvec over this wave's k-window
    f4 A0l = {0,0,0,0}, A0h = {0,0,0,0};
    #pragma unroll 4
    for (int b = 0; b < 16; ++b) {
      const int kb = wv*16 + b;
      const f4 w0 = *(const f4*)(wp0c + kb*256 + lane*4);
      #pragma unroll
      for (int jj = 0; jj < 4; ++jj) {
        const int k = kb*4 + jj;
        const f4 h0lo = *(const f4*)(h0s + k*8);
        const f4 h0hi = *(const f4*)(h0s + k*8 + 4);
        A0l += w0[jj] * h0lo;
        A0h += w0[jj] * h0hi;
      }
    }
    #pragma unroll
    for (int r = 0; r < 4; ++r) {
      za[wv][r][lane]     = A0l[r];
      za[wv][4 + r][lane] = A0h[r];
    }
    // za-arrival: certifies this wave's h0 stage (drained) + za writes
    if (lane == 0)
      __hip_atomic_fetch_add(&zaCtr, 1u, __ATOMIC_ACQ_REL, __HIP_MEMORY_SCOPE_WORKGROUP);

    // wave0: early reduce + publish h0(t+1) + fA (NOT waiting for phase B)
    if (wv == 0 && t + 1 < Lg) {
      while (__hip_atomic_load(&zaCtr, __ATOMIC_ACQUIRE, __HIP_MEMORY_SCOPE_WORKGROUP)
             < 4u*(unsigned)(t + 1))
        __builtin_amdgcn_s_sleep(1);
      __atomic_signal_fence(__ATOMIC_SEQ_CST);
      f4 zA = *(const f4*)&za[0][q*2][gu*4];
      zA += *(const f4*)&za[1][q*2][gu*4];
      zA += *(const f4*)&za[2][q*2][gu*4];
      zA += *(const f4*)&za[3][q*2][gu*4];
      f4 zB = *(const f4*)&za[0][q*2+1][gu*4];
      zB += *(const f4*)&za[1][q*2+1][gu*4];
      zB += *(const f4*)&za[2][q*2+1][gu*4];
      zB += *(const f4*)&za[3][q*2+1][gu*4];
      zA += tpA + cpA;
      zB += tpB + cpB;
      lstm_gate(zA, c0A, h0A, (t+1) < lenA);
      lstm_gate(zB, c0B, h0B, (t+1) < lenB);
      float* pb = ht0 + (buf^1)*GST + puboff;
      if (fast) st64_sc0(pb, h0A, h0B);
      else      st64(pb, h0A, h0B);
      if (lane == 0) {
        if (fast) flag_set_sc0(fgrp + c*32, (unsigned)(t + 2));
        else      flag_set(fgrp + c*32, (unsigned)(t + 2));
      }
    }

    // ======== phase B: h1-dependent work ========
    if (fast) spinB_fast(fgrp, lane, (unsigned)(t + 1));
    else      spinB(fgrp, lane, (unsigned)(t + 1));
    __atomic_signal_fence(__ATOMIC_SEQ_CST);

    // stage OWN 64-k h1 slice
    {
      const float* s1 = ht1 + buf*GST + grp*HTG + wv*512 + lane*8;
      ull c0, c1, c2, c3;
      if (fast) {
        asm volatile(
          "global_load_dwordx2 %0, %4, off sc0\n\t"
          "global_load_dwordx2 %1, %4, off offset:8 sc0\n\t"
          "global_load_dwordx2 %2, %4, off offset:16 sc0\n\t"
          "global_load_dwordx2 %3, %4, off offset:24 sc0\n\t"
          "s_waitcnt vmcnt(0)"
          : "=&v"(c0), "=&v"(c1), "=&v"(c2), "=&v"(c3)
          : "v"(s1)
          : "memory");
      } else {
        c0 = ld64(s1); c1 = ld64(s1+2); c2 = ld64(s1+4); c3 = ld64(s1+6);
      }
      float* d1 = h1s + wv*512 + lane*8;
      *(ull*)(d1)   = c0; *(ull*)(d1+2) = c1; *(ull*)(d1+4) = c2; *(ull*)(d1+6) = c3;
    }

    // a1 matvec: A1 = W1lo*h0(t) + W1up*h1(t-1)
    f4 A1l = {0,0,0,0}, A1h = {0,0,0,0};
    #pragma unroll 2
    for (int b = 0; b < 16; ++b) {
      const int kb = wv*16 + b;
      const f4 wl = *(const f4*)(wp1c + kb*256 + lane*4);
      const f4 wu = *(const f4*)(wp1c + (64 + kb)*256 + lane*4);
      #pragma unroll
      for (int jj = 0; jj < 4; ++jj) {
        const int k = kb*4 + jj;
        const f4 h0lo = *(const f4*)(h0s + k*8);
        const f4 h0hi = *(const f4*)(h0s + k*8 + 4);
        const f4 h1lo = *(const f4*)(h1s + k*8);
        const f4 h1hi = *(const f4*)(h1s + k*8 + 4);
        A1l += wl[jj] * h0lo + wu[jj] * h1lo;
        A1h += wl[jj] * h0hi + wu[jj] * h1hi;
      }
    }

    // projection partial over this wave's k-window (h1 = H1(t-1))
    float pacc = 0.f;
    {
      const int kq = wv*64;
      #pragma unroll 4
      for (int k2 = 0; k2 < 64; k2 += 4) {
        const f4 w4 = *(const f4*)&ldsW[pv][kq + k2];
        pacc = fmaf(h1s[(kq+k2  )*8 + prm], w4.x, pacc);
        pacc = fmaf(h1s[(kq+k2+1)*8 + prm], w4.y, pacc);
        pacc = fmaf(h1s[(kq+k2+2)*8 + prm], w4.z, pacc);
        pacc = fmaf(h1s[(kq+k2+3)*8 + prm], w4.w, pacc);
      }
    }

    #pragma unroll
    for (int r = 0; r < 4; ++r) {
      zb[wv][r][lane]     = A1l[r];
      zb[wv][4 + r][lane] = A1h[r];
    }
    pred[buf][wv][lane] = pacc;
    __syncthreads();      // the ONLY barrier per step (drains vmcnt too)

    if (wv == 1) {
      // gates L1 -> H1(t), publish to buf^1
      f4 zA = *(const f4*)&zb[0][q*2][gu*4];
      zA += *(const f4*)&zb[1][q*2][gu*4];
      zA += *(const f4*)&zb[2][q*2][gu*4];
      zA += *(const f4*)&zb[3][q*2][gu*4];
      f4 zB = *(const f4*)&zb[0][q*2+1][gu*4];
      zB += *(const f4*)&zb[1][q*2+1][gu*4];
      zB += *(const f4*)&zb[2][q*2+1][gu*4];
      zB += *(const f4*)&zb[3][q*2+1][gu*4];
      zA += b1v;
      zB += b1v;
      lstm_gate(zA, c1A, h1A, t < lenA);
      lstm_gate(zB, c1B, h1B, t < lenB);
      float* pb = ht1 + (buf^1)*GST + puboff;
      if (fast) st64_sc0(pb, h1A, h1B);
      else      st64(pb, h1A, h1B);
      if (lane == 0) {
        if (fast) flag_set_sc0(fgrp + c*32 + 16, (unsigned)(t + 2));
        else      flag_set(fgrp + c*32 + 16, (unsigned)(t + 2));
      }
    } else if (wv == 2) {
      // out(t-1) from this step's pred[buf] (computed from H1(t-1))
      if (t > 0) {
        float tot = pred[buf][0][lane] + pred[buf][1][lane]
                  + pred[buf][2][lane] + pred[buf][3][lane] + decb;
        if (t - 1 < plen) outp[(size_t)(t-1)*V_] = tot;
      }
    }
  }

  // ---- epilogue: out(Lg-1) from H1(Lg-1) in buf (Lg&1), fB reaches Lg+1 ----
  spinB(fgrp, lane, (unsigned)(Lg + 1));
  __atomic_signal_fence(__ATOMIC_SEQ_CST);
  {
    const float* s1 = ht1 + (size_t)(Lg & 1)*GST + grp*HTG + wv*512 + lane*8;
    ull b0 = ld64(s1),   b1 = ld64(s1+2);
    ull b2 = ld64(s1+4), b3 = ld64(s1+6);
    float* d1 = h1s + wv*512 + lane*8;
    *(ull*)(d1)   = b0; *(ull*)(d1+2) = b1;
    *(ull*)(d1+4) = b2; *(ull*)(d1+6) = b3;
  }
  {
    float pacc = 0.f;
    const int kq = wv*64;
    #pragma unroll 4
    for (int k2 = 0; k2 < 64; k2 += 4) {
      const f4 w4 = *(const f4*)&ldsW[pv][kq + k2];
      pacc = fmaf(h1s[(kq+k2  )*8 + prm], w4.x, pacc);
      pacc = fmaf(h1s[(kq+k2+1)*8 + prm], w4.y, pacc);
      pacc = fmaf(h1s[(kq+k2+2)*8 + prm], w4.z, pacc);
      pacc = fmaf(h1s[(kq+k2+3)*8 + prm], w4.w, pacc);
    }
    pred[Lg & 1][wv][lane] = pacc;
  }
  __syncthreads();
  if (wv == 2) {
    float tot = pred[Lg & 1][0][lane] + pred[Lg & 1][1][lane]
              + pred[Lg & 1][2][lane] + pred[Lg & 1][3][lane] + decb;
    if (Lg - 1 < plen) outp[(size_t)(Lg-1)*V_] = tot;
  }
}

// ============ launch ============

extern "C" void kernel_launch(void* const* d_in, const int* in_sizes, int n_in,
                              void* d_out, int out_size, void* d_ws, size_t ws_size,
                              hipStream_t stream) {
  const int*   toks  = (const int*)d_in[0];
  const int*   lens  = (const int*)d_in[1];
  const int*   clus  = (const int*)d_in[2];
  const float* cemb  = (const float*)d_in[3];
  const float* clemb = (const float*)d_in[4];
  const float* W0    = (const float*)d_in[5];
  const float* b0    = (const float*)d_in[6];
  const float* W1    = (const float*)d_in[7];
  const float* b1    = (const float*)d_in[8];
  const float* dW    = (const float*)d_in[9];
  const float* decB  = (const float*)d_in[10];
  float* out = (float*)d_out;
  float* ws  = (float*)d_ws;

  // zero output (masked positions must be exactly 0), h buffers (H1(-1)=0),
  // and the flag block (incl. xcc slots)
  hipMemsetAsync(out, 0, (size_t)B_*T_*V_*sizeof(float), stream);
  hipMemsetAsync(ws, 0, (size_t)(OFF_BAR + BARSZ)*sizeof(float), stream);

  prep_pack<<<1024, 256, 0, stream>>>(W0, W1, dW, b1, ws);
  prep_tok <<<V_*4, 256, 0, stream>>>(cemb, W0, ws);
  prep_clus<<<B_*4, 256, 0, stream>>>(clus, clemb, W0, b0, ws);
  prep_sort<<<1, 256, 0, stream>>>(lens, ws);
  lstm_persist<<<NWG, 256, 0, stream>>>(toks, lens, decB, ws, out);
}

// Round 14
// 4517.434 us; speedup vs baseline: 1.3971x; 1.3272x over previous
//
#include <hip/hip_runtime.h>

#define B_ 256
#define T_ 512
#define V_ 128
#define E_ 128
#define H_ 256
#define FH 1024

#define GROUPS 32
#define RPG 8      // batch rows per group
#define CWG 16     // column-WGs per group
#define NWG (GROUPS*CWG)   // 512 = 2 blocks/CU

#define HTG 2048   // floats: one group's h, one layer, one buffer ([16c][16gu][8 r'])
#define GST (GROUPS*HTG)   // 65536

typedef float f4 __attribute__((ext_vector_type(4)));
typedef unsigned long long ull;

// ---- workspace layout (float offsets) ----
#define OFF_HT0  0                              // h0 [2buf][grp][c][gu][r']
#define OFF_HT1  (OFF_HT0 + 2*GST)
#define OFF_BAR  (OFF_HT1 + 2*GST)              // 32 groups * 1024 uints (4KB/grp)
#define BARSZ    (GROUPS*1024)                  // fA_c at [c*32], fB_c at [c*32+16]; xcc at [512+c]
#define OFF_TP   (OFF_BAR + BARSZ)              // TokProj [V][1024] packed
#define OFF_CP   (OFF_TP + V_*FH)               // ClusProj [B][1024] packed (+b0)
#define OFF_WP0  (OFF_CP + B_*FH)               // W0h x4-packed [16c][64kb][64lane][4j]
#define OFF_WP1  (OFF_WP0 + CWG*64*64*4)        // W1  x4-packed [16c][128kb][64lane][4j]
#define OFF_DWT  (OFF_WP1 + CWG*128*64*4)       // decoderW^T [128v][256k]
#define OFF_B1   (OFF_DWT + V_*H_)              // b1 packed [1024]
#define OFF_PERM (OFF_B1 + FH)                  // row permutation [256] (ints)

// packed column order: local col = u*4+g  ->  global z-col G = g*256 + c*16 + u
__device__ __forceinline__ int gcol(int c, int col) {
  int u = col >> 2, g = col & 3;
  return g*256 + c*16 + u;
}

__device__ __forceinline__ float sigm(float x){ return 1.f/(1.f+__expf(-x)); }
__device__ __forceinline__ float tanh_(float x){ return 1.f - 2.f/(1.f+__expf(2.f*x)); }

// ============ prep kernels ============

__global__ void prep_pack(const float* __restrict__ W0, const float* __restrict__ W1,
                          const float* __restrict__ dW, const float* __restrict__ b1,
                          float* __restrict__ ws) {
  float* wp0 = ws + OFF_WP0; float* wp1 = ws + OFF_WP1;
  float* dwT = ws + OFF_DWT; float* b1p = ws + OFF_B1;
  const int N0 = CWG*64*64*4;     // 262144
  const int N1 = CWG*128*64*4;    // 524288
  const int N2 = V_*H_;           // 32768
  const int N3 = FH;              // 1024
  const int total = N0+N1+N2+N3;
  for (int i = blockIdx.x*blockDim.x + threadIdx.x; i < total; i += gridDim.x*blockDim.x) {
    if (i < N0) {
      int cc = i >> 14; int rem = i & 16383;
      int kb = rem >> 8; int ln = (rem >> 2) & 63; int j = i & 3;
      int k = kb*4 + j;
      wp0[i] = W0[(E_+H_+k)*FH + gcol(cc, ln)];          // W0 h0-rows
    } else if (i < N0+N1) {
      int idx = i - N0;
      int cc = idx >> 15; int rem = idx & 32767;
      int kb = rem >> 8; int ln = (rem >> 2) & 63; int j = idx & 3;
      int k2 = kb*4 + j;                                  // 0..255 h0n, 256..511 h1
      wp1[idx] = W1[k2*FH + gcol(cc, ln)];
    } else if (i < N0+N1+N2) {
      int l = i - N0 - N1;
      int v = l >> 8, k = l & 255;
      dwT[l] = dW[k*V_ + v];
    } else {
      int cc2 = i - N0 - N1 - N2;
      b1p[cc2] = b1[gcol(cc2>>6, cc2&63)];
    }
  }
}

__global__ void prep_tok(const float* __restrict__ cemb, const float* __restrict__ W0,
                         float* __restrict__ ws) {
  __shared__ float ce[E_];
  float* TP = ws + OFF_TP;
  int v = blockIdx.x >> 2, q = blockIdx.x & 3;
  int tid = threadIdx.x;
  if (tid < E_) ce[tid] = cemb[v*E_ + tid];
  __syncthreads();
  int ccol = q*256 + tid;
  int G = gcol(ccol>>6, ccol&63);
  float acc = 0.f;
  for (int e = 0; e < E_; ++e) acc = fmaf(ce[e], W0[e*FH + G], acc);
  TP[v*FH + ccol] = acc;
}

__global__ void prep_clus(const int* __restrict__ clus, const float* __restrict__ clemb,
                          const float* __restrict__ W0, const float* __restrict__ b0,
                          float* __restrict__ ws) {
  __shared__ float ce[H_];
  float* CP = ws + OFF_CP;
  int b = blockIdx.x >> 2, q = blockIdx.x & 3;
  int tid = threadIdx.x;
  int cl = clus[b];
  ce[tid] = clemb[(long long)cl*H_ + tid];
  __syncthreads();
  int ccol = q*256 + tid;
  int G = gcol(ccol>>6, ccol&63);
  float acc = b0[G];
  for (int e = 0; e < H_; ++e) acc = fmaf(ce[e], W0[(E_+e)*FH + G], acc);
  CP[b*FH + ccol] = acc;
}

// rank-sort 256 rows by length, DESCENDING (deterministic tie-break by index).
__global__ void prep_sort(const int* __restrict__ lens, float* __restrict__ ws) {
  __shared__ int sl[B_];
  int* perm = (int*)(ws + OFF_PERM);
  const int i = threadIdx.x;
  sl[i] = lens[i];
  __syncthreads();
  const int li = sl[i];
  int rank = 0;
  for (int j = 0; j < B_; ++j) {
    const int lj = sl[j];
    rank += (lj > li) || (lj == li && j < i);
  }
  perm[rank] = i;
}

// ============ sync & staging primitives ============
// SLOW (agent) path: proven device-scope protocol. FAST (sc0) path:
// L1-bypass / XCD-L2-coherent — valid only when all 16 WGs of the group share
// one XCD (runtime-verified via HW_REG_XCC_ID; per-group uniform decision).

__device__ __forceinline__ void st64(float* p, float a, float b) {
  float2 t; t.x = a; t.y = b;
  __hip_atomic_store((ull*)p, __builtin_bit_cast(ull, t),
                     __ATOMIC_RELAXED, __HIP_MEMORY_SCOPE_AGENT);
}

__device__ __forceinline__ void st64_sc0(float* p, float a, float b) {
  float2 t; t.x = a; t.y = b;
  ull v = __builtin_bit_cast(ull, t);
  asm volatile("global_store_dwordx2 %0, %1, off sc0" :: "v"(p), "v"(v) : "memory");
}

__device__ __forceinline__ ull ld64(const void* p) {
  return __hip_atomic_load((const ull*)p, __ATOMIC_RELAXED, __HIP_MEMORY_SCOPE_AGENT);
}

// single 32b sc0 load with fused drain (load+wait in ONE asm stmt)
__device__ __forceinline__ unsigned ld32_sc0(const unsigned* p) {
  unsigned v;
  asm volatile("global_load_dword %0, %1, off sc0\n\t"
               "s_waitcnt vmcnt(0)"
               : "=v"(v) : "v"(p) : "memory");
  return v;
}

// flag publish: vmcnt(0) drains this wave's prior h-stores (and staging
// loads, preserving the buffer-overwrite proof: flag >= t+2 implies
// stage-of-buf(t) completed), then relaxed flag store at the matching scope.
__device__ __forceinline__ void flag_set(unsigned* p, unsigned v) {
  asm volatile("s_waitcnt vmcnt(0)" ::: "memory");
  __hip_atomic_store(p, v, __ATOMIC_RELAXED, __HIP_MEMORY_SCOPE_AGENT);
}
__device__ __forceinline__ void flag_set_sc0(unsigned* p, unsigned v) {
  asm volatile("s_waitcnt vmcnt(0)" ::: "memory");
  asm volatile("global_store_dword %0, %1, off sc0" :: "v"(p), "v"(v) : "memory");
}

// PER-WAVE poll (all 4 waves): flags one 64B line per (c, type): fA at c*32,
// fB at c*32+16. lanes 0-31 cover fA lines, 32-63 fB lines.
__device__ __forceinline__ void spinAB(const unsigned* fgrp, int lane, unsigned tgt) {
  const unsigned* p = fgrp + (lane & 15)*32 + ((lane >> 5) << 4);
  unsigned v = __hip_atomic_load(p, __ATOMIC_RELAXED, __HIP_MEMORY_SCOPE_AGENT);
  while (!__all((int)(v >= tgt))) {
    __builtin_amdgcn_s_sleep(4);
    v = __hip_atomic_load(p, __ATOMIC_RELAXED, __HIP_MEMORY_SCOPE_AGENT);
  }
}
// fast variant: sc0 polls, tighter backoff; every 8th poll agent-scope safety net
__device__ __forceinline__ void spinAB_fast(const unsigned* fgrp, int lane, unsigned tgt) {
  const unsigned* p = fgrp + (lane & 15)*32 + ((lane >> 5) << 4);
  unsigned v = ld32_sc0(p);
  int it = 0;
  while (!__all((int)(v >= tgt))) {
    __builtin_amdgcn_s_sleep(2);
    ++it;
    v = (it & 7) ? ld32_sc0(p)
                 : __hip_atomic_load(p, __ATOMIC_RELAXED, __HIP_MEMORY_SCOPE_AGENT);
  }
}

// epilogue: fB lines only (agent — runs once, keep it safe)
__device__ __forceinline__ void spinB(const unsigned* fgrp, int lane, unsigned tgt) {
  const unsigned* p = fgrp + (lane & 15)*32 + 16;
  unsigned v = __hip_atomic_load(p, __ATOMIC_RELAXED, __HIP_MEMORY_SCOPE_AGENT);
  while (!__all((int)(v >= tgt))) {
    __builtin_amdgcn_s_sleep(4);
    v = __hip_atomic_load(p, __ATOMIC_RELAXED, __HIP_MEMORY_SCOPE_AGENT);
  }
}

__device__ __forceinline__ void lstm_gate(const f4 z, float& cc, float& hh, const bool upd) {
  float ci = sigm(z.x);
  float cj = tanh_(z.y);
  float cf = sigm(z.z + 1.f);
  float co = sigm(z.w);
  float cn = fmaf(cc, cf, ci*cj);
  float hn = tanh_(cn)*co;
  if (upd) { cc = cn; hh = hn; }
}

// ============ main persistent kernel ============
//
// R10 winner (per-wave spin, single barrier/step, sc0 XCD-local fast path,
// length-sorted groups, 2 blocks/CU) + ONE change: LONG-SHORT CO-RESIDENCY
// PAIRING. loc = grp&3 maps to length-octile via Gray flip
//   oct = loc ^ (loc>>1)   (0->0, 1->1, 2->3, 3->2)
// Under packed fill (j, j+1 co-resident, loc differs by 2) octile pairs
// become (0,3),(1,2): the longest groups share CUs with the SHORTEST octile,
// whose partner retires after ~64 steps -> the critical groups run the
// remaining ~85% of their steps with sole CU occupancy (uncontended issue,
// exclusive L1). Under breadth-first fill the mapping is unchanged (neutral).

__global__ __launch_bounds__(256, 2) void lstm_persist(
    const int* __restrict__ toks, const int* __restrict__ lens,
    const float* __restrict__ decB, float* __restrict__ ws, float* __restrict__ out)
{
  const int blk  = blockIdx.x;
  const int xcd  = blk & 7;
  const int j    = blk >> 3;                               // 0..63 within XCD
  const int grp  = (xcd << 2) | ((j & 1) << 1) | (j >> 5); // 0..31, XCD-local
  const int c    = (j >> 1) & 15;                          // column-WG 0..15
  const int tid  = threadIdx.x;
  const int lane = tid & 63;
  const int wv   = tid >> 6;
  const int cof  = c*64;

  // sorted-group id with Gray-flipped octile: longest pairs with shortest.
  const int loc   = grp & 3;
  const int oct   = loc ^ (loc >> 1);          // 0,1,3,2
  const int sgrp  = (oct << 3) | (grp >> 2);
  const int rbase = sgrp*RPG;
  const int* perm = (const int*)(ws + OFF_PERM);

  float* ht0 = ws + OFF_HT0;
  float* ht1 = ws + OFF_HT1;
  unsigned* fgrp = (unsigned*)(ws + OFF_BAR) + grp*1024;
  const float* TP   = ws + OFF_TP;
  const float* CP   = ws + OFF_CP;
  const float* wp0c = ws + OFF_WP0 + c*(64*64*4);
  const float* wp1c = ws + OFF_WP1 + c*(128*64*4);
  const float* dwT  = ws + OFF_DWT;
  const float* b1p  = ws + OFF_B1;

  __shared__ __align__(16) float h0s[2048];     // [256k][8 r'], wave-private slices
  __shared__ __align__(16) float h1s[2048];
  __shared__ __align__(16) float za[4][8][64];  // z0 partials (flag-protected)
  __shared__ __align__(16) float zb[4][8][64];  // z1 partials (flag-protected)
  __shared__ float ldsW[8][260];                // decoderW slice [v][k], padded
  __shared__ float pred[2][4][64];              // proj partials, dbuf by t&1
  __shared__ unsigned fastSh;

  // stage decoder weight slice (v = c*8 .. c*8+7)
  for (int i = tid; i < 8*H_; i += 256)
    ldsW[i>>8][i&255] = dwT[(c*8 + (i>>8))*H_ + (i&255)];

  // ---- runtime XCD-colocation check (agent scope; all 512 WGs co-resident)
  unsigned xcc;
  asm volatile("s_getreg_b32 %0, hwreg(HW_REG_XCC_ID)" : "=s"(xcc));
  if (tid == 0)
    __hip_atomic_store(fgrp + 512 + c, xcc + 1u, __ATOMIC_RELAXED, __HIP_MEMORY_SCOPE_AGENT);
  if (wv == 0) {
    const unsigned* p = fgrp + 512 + (lane & 15);
    unsigned v = __hip_atomic_load(p, __ATOMIC_RELAXED, __HIP_MEMORY_SCOPE_AGENT);
    while (!__all((int)(v != 0u))) {
      __builtin_amdgcn_s_sleep(8);
      v = __hip_atomic_load(p, __ATOMIC_RELAXED, __HIP_MEMORY_SCOPE_AGENT);
    }
    const bool same = __all((int)(v == xcc + 1u));
    if (lane == 0) fastSh = same ? 1u : 0u;
  }

  // ---- group max length (all lanes), through the permutation ----
  int Lg = lens[perm[rbase + (lane & 7)]];
  Lg = max(Lg, __shfl_xor(Lg, 1));
  Lg = max(Lg, __shfl_xor(Lg, 2));
  Lg = max(Lg, __shfl_xor(Lg, 4));

  // ---- gate-lane constants (wave0 = layer0, wave1 = layer1) ----
  const int gu = lane & 15, q = lane >> 4;   // unit 0..15, q 0..3 (rows q, q+4)
  const int rowA = perm[rbase + q], rowB = perm[rbase + q + 4];
  const int lenA = lens[rowA], lenB = lens[rowB];
  const int* tokApt = toks + rowA*T_;
  const int* tokBpt = toks + rowB*T_;
  const f4 cpA = *(const f4*)(CP + rowA*FH + cof + gu*4);
  const f4 cpB = *(const f4*)(CP + rowB*FH + cof + gu*4);
  const f4 b1v = *(const f4*)(b1p + cof + gu*4);
  const int puboff = grp*HTG + (c*16 + gu)*8 + q*2;   // r' = 2q (+1)
  float c0A = 0.f, h0A = 0.f, c0B = 0.f, h0B = 0.f;   // wave0 L0 state
  float c1A = 0.f, h1A = 0.f, c1B = 0.f, h1B = 0.f;   // wave1 L1 state

  // ---- projection constants ----
  const int pm = lane >> 3, pv = lane & 7;            // row 0..7, vocab-col 0..7
  const int prm = (pm < 4) ? pm*2 : (pm-4)*2 + 1;     // r' of row pm
  const int prow = perm[rbase + pm];
  const int plen = lens[prow];
  const float decb = decB[c*8 + pv];
  float* outp = out + (size_t)prow*T_*V_ + c*8 + pv;

  __syncthreads();   // ldsW staged + fastSh decided
  const bool fast = (fastSh != 0u);

  // ---- prologue: H0(0) from TP+CP; H1(-1)=0 via pre-zeroed ws ----
  if (wv == 0) {
    f4 zAv = *(const f4*)(TP + tokApt[0]*FH + cof + gu*4) + cpA;
    f4 zBv = *(const f4*)(TP + tokBpt[0]*FH + cof + gu*4) + cpB;
    lstm_gate(zAv, c0A, h0A, 0 < lenA);
    lstm_gate(zBv, c0B, h0B, 0 < lenB);
    if (fast) st64_sc0(ht0 + puboff, h0A, h0B);
    else      st64(ht0 + puboff, h0A, h0B);       // buf0
    if (lane == 0) {
      if (fast) flag_set_sc0(fgrp + c*32, 1u);
      else      flag_set(fgrp + c*32, 1u);
    }
  } else if (wv == 1) {
    if (lane == 0) {
      if (fast) flag_set_sc0(fgrp + c*32 + 16, 1u);
      else      flag_set(fgrp + c*32 + 16, 1u);   // h1 buf0 pre-zeroed
    }
  }

  for (int t = 0; t < Lg; ++t) {
    const int buf = t & 1;

    // TP prefetch for next-step z0 (in flight across the spin)
    f4 tpA = {0,0,0,0}, tpB = {0,0,0,0};
    if (wv == 0 && t + 1 < Lg) {
      tpA = *(const f4*)(TP + tokApt[t+1]*FH + cof + gu*4);
      tpB = *(const f4*)(TP + tokBpt[t+1]*FH + cof + gu*4);
    }

    // ---- per-wave spin: {H0(t), H1(t-1)} both ready (no barrier after) ----
    if (fast) spinAB_fast(fgrp, lane, (unsigned)(t + 1));
    else      spinAB(fgrp, lane, (unsigned)(t + 1));
    __atomic_signal_fence(__ATOMIC_SEQ_CST);

    // ---- stage OWN 64-k slice (wave-private) ----
    {
      const float* s0 = ht0 + buf*GST + grp*HTG + wv*512 + lane*8;
      const float* s1 = ht1 + buf*GST + grp*HTG + wv*512 + lane*8;
      ull a0, a1, a2, a3, c0, c1, c2, c3;
      if (fast) {
        asm volatile(
          "global_load_dwordx2 %0, %8, off sc0\n\t"
          "global_load_dwordx2 %1, %8, off offset:8 sc0\n\t"
          "global_load_dwordx2 %2, %8, off offset:16 sc0\n\t"
          "global_load_dwordx2 %3, %8, off offset:24 sc0\n\t"
          "global_load_dwordx2 %4, %9, off sc0\n\t"
          "global_load_dwordx2 %5, %9, off offset:8 sc0\n\t"
          "global_load_dwordx2 %6, %9, off offset:16 sc0\n\t"
          "global_load_dwordx2 %7, %9, off offset:24 sc0\n\t"
          "s_waitcnt vmcnt(0)"
          : "=&v"(a0), "=&v"(a1), "=&v"(a2), "=&v"(a3),
            "=&v"(c0), "=&v"(c1), "=&v"(c2), "=&v"(c3)
          : "v"(s0), "v"(s1)
          : "memory");
      } else {
        a0 = ld64(s0);   a1 = ld64(s0+2); a2 = ld64(s0+4); a3 = ld64(s0+6);
        c0 = ld64(s1);   c1 = ld64(s1+2); c2 = ld64(s1+4); c3 = ld64(s1+6);
      }
      float* d0 = h0s + wv*512 + lane*8;
      float* d1 = h1s + wv*512 + lane*8;
      *(ull*)(d0)   = a0; *(ull*)(d0+2) = a1; *(ull*)(d0+4) = a2; *(ull*)(d0+6) = a3;
      *(ull*)(d1)   = c0; *(ull*)(d1+2) = c1; *(ull*)(d1+4) = c2; *(ull*)(d1+6) = c3;
    }

    // ---- fused matvec over this wave's k-window:
    //      A0 = W0h*h0; A1 = W1lo*h0 + W1up*h1 (rows in r' order) ----
    f4 A0l = {0,0,0,0}, A0h = {0,0,0,0}, A1l = {0,0,0,0}, A1h = {0,0,0,0};
    #pragma unroll 2
    for (int b = 0; b < 16; ++b) {
      const int kb = wv*16 + b;
      const f4 w0 = *(const f4*)(wp0c + kb*256 + lane*4);
      const f4 wl = *(const f4*)(wp1c + kb*256 + lane*4);
      const f4 wu = *(const f4*)(wp1c + (64 + kb)*256 + lane*4);
      #pragma unroll
      for (int jj = 0; jj < 4; ++jj) {
        const int k = kb*4 + jj;
        const float* hb0 = h0s + k*8;
        const float* hb1 = h1s + k*8;
        const f4 h0lo = *(const f4*)(hb0);
        const f4 h0hi = *(const f4*)(hb0 + 4);
        const f4 h1lo = *(const f4*)(hb1);
        const f4 h1hi = *(const f4*)(hb1 + 4);
        const float w0j = w0[jj], wlj = wl[jj], wuj = wu[jj];
        A0l += w0j * h0lo;  A0h += w0j * h0hi;
        A1l += wlj * h0lo + wuj * h1lo;
        A1h += wlj * h0hi + wuj * h1hi;
      }
    }

    // ---- projection partial over this wave's k-window (h1 = H1(t-1)) ----
    float pacc = 0.f;
    {
      const int kq = wv*64;
      #pragma unroll 4
      for (int k2 = 0; k2 < 64; k2 += 4) {
        const f4 w4 = *(const f4*)&ldsW[pv][kq + k2];
        pacc = fmaf(h1s[(kq+k2  )*8 + prm], w4.x, pacc);
        pacc = fmaf(h1s[(kq+k2+1)*8 + prm], w4.y, pacc);
        pacc = fmaf(h1s[(kq+k2+2)*8 + prm], w4.z, pacc);
        pacc = fmaf(h1s[(kq+k2+3)*8 + prm], w4.w, pacc);
      }
    }

    #pragma unroll
    for (int r = 0; r < 4; ++r) {
      za[wv][r][lane]     = A0l[r];
      za[wv][4 + r][lane] = A0h[r];
      zb[wv][r][lane]     = A1l[r];
      zb[wv][4 + r][lane] = A1h[r];
    }
    pred[buf][wv][lane] = pacc;
    __syncthreads();      // the ONLY barrier per step (drains vmcnt too)

    if (wv == 0) {
      // gates L0 -> H0(t+1), publish to buf^1   (rows q -> r'=2q, q+4 -> 2q+1)
      if (t + 1 < Lg) {
        f4 zA = *(const f4*)&za[0][q*2][gu*4];
        zA += *(const f4*)&za[1][q*2][gu*4];
        zA += *(const f4*)&za[2][q*2][gu*4];
        zA += *(const f4*)&za[3][q*2][gu*4];
        f4 zB = *(const f4*)&za[0][q*2+1][gu*4];
        zB += *(const f4*)&za[1][q*2+1][gu*4];
        zB += *(const f4*)&za[2][q*2+1][gu*4];
        zB += *(const f4*)&za[3][q*2+1][gu*4];
        zA += tpA + cpA;
        zB += tpB + cpB;
        lstm_gate(zA, c0A, h0A, (t+1) < lenA);
        lstm_gate(zB, c0B, h0B, (t+1) < lenB);
        float* pb = ht0 + (buf^1)*GST + puboff;
        if (fast) st64_sc0(pb, h0A, h0B);
        else      st64(pb, h0A, h0B);
        if (lane == 0) {
          if (fast) flag_set_sc0(fgrp + c*32, (unsigned)(t + 2));
          else      flag_set(fgrp + c*32, (unsigned)(t + 2));
        }
      }
    } else if (wv == 1) {
      // gates L1 -> H1(t), publish to buf^1
      f4 zA = *(const f4*)&zb[0][q*2][gu*4];
      zA += *(const f4*)&zb[1][q*2][gu*4];
      zA += *(const f4*)&zb[2][q*2][gu*4];
      zA += *(const f4*)&zb[3][q*2][gu*4];
      f4 zB = *(const f4*)&zb[0][q*2+1][gu*4];
      zB += *(const f4*)&zb[1][q*2+1][gu*4];
      zB += *(const f4*)&zb[2][q*2+1][gu*4];
      zB += *(const f4*)&zb[3][q*2+1][gu*4];
      zA += b1v;
      zB += b1v;
      lstm_gate(zA, c1A, h1A, t < lenA);
      lstm_gate(zB, c1B, h1B, t < lenB);
      float* pb = ht1 + (buf^1)*GST + puboff;
      if (fast) st64_sc0(pb, h1A, h1B);
      else      st64(pb, h1A, h1B);
      if (lane == 0) {
        if (fast) flag_set_sc0(fgrp + c*32 + 16, (unsigned)(t + 2));
        else      flag_set(fgrp + c*32 + 16, (unsigned)(t + 2));
      }
    } else if (wv == 2) {
      // out(t-1) from this step's pred[buf] (computed from H1(t-1))
      if (t > 0) {
        float tot = pred[buf][0][lane] + pred[buf][1][lane]
                  + pred[buf][2][lane] + pred[buf][3][lane] + decb;
        if (t - 1 < plen) outp[(size_t)(t-1)*V_] = tot;
      }
    }
  }

  // ---- epilogue: out(Lg-1) from H1(Lg-1) in buf (Lg&1), fB reaches Lg+1 ----
  spinB(fgrp, lane, (unsigned)(Lg + 1));
  __atomic_signal_fence(__ATOMIC_SEQ_CST);
  {
    const float* s1 = ht1 + (size_t)(Lg & 1)*GST + grp*HTG + wv*512 + lane*8;
    ull b0 = ld64(s1),   b1 = ld64(s1+2);
    ull b2 = ld64(s1+4), b3 = ld64(s1+6);
    float* d1 = h1s + wv*512 + lane*8;
    *(ull*)(d1)   = b0; *(ull*)(d1+2) = b1;
    *(ull*)(d1+4) = b2; *(ull*)(d1+6) = b3;
  }
  {
    float pacc = 0.f;
    const int kq = wv*64;
    #pragma unroll 4
    for (int k2 = 0; k2 < 64; k2 += 4) {
      const f4 w4 = *(const f4*)&ldsW[pv][kq + k2];
      pacc = fmaf(h1s[(kq+k2  )*8 + prm], w4.x, pacc);
      pacc = fmaf(h1s[(kq+k2+1)*8 + prm], w4.y, pacc);
      pacc = fmaf(h1s[(kq+k2+2)*8 + prm], w4.z, pacc);
      pacc = fmaf(h1s[(kq+k2+3)*8 + prm], w4.w, pacc);
    }
    pred[Lg & 1][wv][lane] = pacc;
  }
  __syncthreads();
  if (wv == 2) {
    float tot = pred[Lg & 1][0][lane] + pred[Lg & 1][1][lane]
              + pred[Lg & 1][2][lane] + pred[Lg & 1][3][lane] + decb;
    if (Lg - 1 < plen) outp[(size_t)(Lg-1)*V_] = tot;
  }
}

// ============ launch ============

extern "C" void kernel_launch(void* const* d_in, const int* in_sizes, int n_in,
                              void* d_out, int out_size, void* d_ws, size_t ws_size,
                              hipStream_t stream) {
  const int*   toks  = (const int*)d_in[0];
  const int*   lens  = (const int*)d_in[1];
  const int*   clus  = (const int*)d_in[2];
  const float* cemb  = (const float*)d_in[3];
  const float* clemb = (const float*)d_in[4];
  const float* W0    = (const float*)d_in[5];
  const float* b0    = (const float*)d_in[6];
  const float* W1    = (const float*)d_in[7];
  const float* b1    = (const float*)d_in[8];
  const float* dW    = (const float*)d_in[9];
  const float* decB  = (const float*)d_in[10];
  float* out = (float*)d_out;
  float* ws  = (float*)d_ws;

  // zero output (masked positions must be exactly 0), h buffers (H1(-1)=0),
  // and the flag block (incl. xcc slots)
  hipMemsetAsync(out, 0, (size_t)B_*T_*V_*sizeof(float), stream);
  hipMemsetAsync(ws, 0, (size_t)(OFF_BAR + BARSZ)*sizeof(float), stream);

  prep_pack<<<1024, 256, 0, stream>>>(W0, W1, dW, b1, ws);
  prep_tok <<<V_*4, 256, 0, stream>>>(cemb, W0, ws);
  prep_clus<<<B_*4, 256, 0, stream>>>(clus, clemb, W0, b0, ws);
  prep_sort<<<1, 256, 0, stream>>>(lens, ws);
  lstm_persist<<<NWG, 256, 0, stream>>>(toks, lens, decB, ws, out);
}